// Round 1
// baseline (114.040 us; speedup 1.0000x reference)
//
#include <hip/hip_runtime.h>
#include <hip/hip_bf16.h>

#define B_    4
#define CIN   64
#define E_    75000
#define K_    5
#define COUT  128
#define KTOT  320   // K_*CIN
#define MTILE 64
#define NT_X  1172  // ceil(E_/MTILE)

typedef __attribute__((ext_vector_type(8))) short short8;
typedef __attribute__((ext_vector_type(4))) float f32x4;

static __device__ __forceinline__ unsigned short f2bf(float f) {
    __hip_bfloat16 h = __float2bfloat16(f);
    union { __hip_bfloat16 h; unsigned short u; } cv; cv.h = h; return cv.u;
}
static __device__ __forceinline__ float bflo(unsigned int v) { return __uint_as_float(v << 16); }
static __device__ __forceinline__ float bfhi(unsigned int v) { return __uint_as_float(v & 0xffff0000u); }
static __device__ __forceinline__ unsigned int pack2(float lo, float hi) {
    return (unsigned int)f2bf(lo) | ((unsigned int)f2bf(hi) << 16);
}

// ---------------- Kernel 1: x (B,CIN,E) f32 -> f (B,E,CIN) bf16 ----------------
__global__ __launch_bounds__(256) void transpose_kernel(const float* __restrict__ x,
                                                        unsigned short* __restrict__ f) {
    __shared__ float lds[64][65];
    const int b  = blockIdx.y;
    const int e0 = blockIdx.x * MTILE;
    const int tid = threadIdx.x;
    const int lane_e = tid & 63;
    const int cg = tid >> 6;                 // 0..3 channel group
    const int egc = min(e0 + lane_e, E_ - 1);
    const float* xb = x + (size_t)b * CIN * E_;
#pragma unroll
    for (int i = 0; i < 16; ++i) {
        int c = cg * 16 + i;
        lds[lane_e][c] = xb[(size_t)c * E_ + egc];
    }
    __syncthreads();
    const int e = tid >> 2;                  // 0..63
    const int q = tid & 3;                   // channels q*16..q*16+15
    if (e0 + e < E_) {
        unsigned short tmp[16] __attribute__((aligned(16)));
#pragma unroll
        for (int i = 0; i < 16; ++i) tmp[i] = f2bf(lds[e][q * 16 + i]);
        unsigned short* dst = f + ((size_t)b * E_ + e0 + e) * CIN + q * 16;
        *(short8*)dst       = *(short8*)&tmp[0];
        *(short8*)(dst + 8) = *(short8*)&tmp[8];
    }
}

// ------- Kernel 2: W (COUT, KTOT) f32 -> fragment-ordered bf16 Wf -------
// frag t = (s*8 + fidx)*64 + lane ; elem j = W[fidx*16 + (lane&15)][s*32 + (lane>>4)*8 + j]
__global__ void wconv_kernel(const float* __restrict__ W, unsigned short* __restrict__ Wf) {
    int t = blockIdx.x * 256 + threadIdx.x;
    if (t >= 10 * 8 * 64) return;
    int lane = t & 63;
    int fidx = (t >> 6) & 7;
    int s    = t >> 9;
    int row = fidx * 16 + (lane & 15);
    int col = s * 32 + (lane >> 4) * 8;
    const float* src = W + (size_t)row * KTOT + col;
    unsigned short tmp[8] __attribute__((aligned(16)));
#pragma unroll
    for (int j = 0; j < 8; ++j) tmp[j] = f2bf(src[j]);
    *(short8*)(Wf + (size_t)t * 8) = *(short8*)tmp;
}

// ---------------- Kernel 3: fused gather + G build + MFMA GEMM ----------------
__global__ __launch_bounds__(256) void meshconv_kernel(
    const unsigned short* __restrict__ f, const int* __restrict__ em,
    const unsigned short* __restrict__ Wf, const float* __restrict__ bias,
    float* __restrict__ out) {
    __shared__ unsigned short Gs[64][328];   // 320 + 8 pad (2-way-free banks)
    __shared__ int sidx[64][K_];

    const int b  = blockIdx.y;
    const int e0 = blockIdx.x * MTILE;
    const int tid = threadIdx.x;
    const int w = tid >> 6, lane = tid & 63;

    // ---- load edge indices (320 ints, clamp reads for the tail block) ----
    {
        size_t base = ((size_t)b * E_ + e0) * K_;
        size_t maxi = (size_t)B_ * E_ * K_ - 1;
        ((int*)sidx)[tid] = em[min(base + tid, maxi)];
        if (tid < 64) ((int*)sidx)[256 + tid] = em[min(base + 256 + tid, maxi)];
    }
    __syncthreads();

    // ---- gather + build G in LDS (bf16) ----
    {
        const unsigned short* fb = f + (size_t)b * E_ * CIN;
        const int eo = lane >> 5;            // which edge of the pair
        const int cu = lane & 31;            // uint (=2 channels) index
#pragma unroll
        for (int ep = 0; ep < 8; ++ep) {
            int el = w * 16 + ep * 2 + eo;   // local edge 0..63
            unsigned int g[K_];
#pragma unroll
            for (int k = 0; k < K_; ++k) {
                int idx = sidx[el][k];
                g[k] = *(const unsigned int*)(fb + (size_t)idx * CIN + cu * 2);
            }
            unsigned int* grow = (unsigned int*)&Gs[el][0];
            grow[0 * 32 + cu] = g[0];
            grow[1 * 32 + cu] = pack2(bflo(g[1]) + bflo(g[3]), bfhi(g[1]) + bfhi(g[3]));
            grow[2 * 32 + cu] = pack2(bflo(g[2]) + bflo(g[4]), bfhi(g[2]) + bfhi(g[4]));
            grow[3 * 32 + cu] = pack2(fabsf(bflo(g[1]) - bflo(g[3])), fabsf(bfhi(g[1]) - bfhi(g[3])));
            grow[4 * 32 + cu] = pack2(fabsf(bflo(g[2]) - bflo(g[4])), fabsf(bfhi(g[2]) - bfhi(g[4])));
        }
    }
    __syncthreads();

    // ---- MFMA: 4 waves in 2x2; each wave 32 rows x 64 cols ----
    const int wr = w >> 1, wc = w & 1;
    const int l15 = lane & 15, l4 = lane >> 4;
    f32x4 acc[2][4];
#pragma unroll
    for (int mf = 0; mf < 2; ++mf)
#pragma unroll
        for (int nf = 0; nf < 4; ++nf) acc[mf][nf] = (f32x4){0.f, 0.f, 0.f, 0.f};

#pragma unroll
    for (int s = 0; s < 10; ++s) {
        short8 af[2], bfr[4];
#pragma unroll
        for (int mf = 0; mf < 2; ++mf)
            af[mf] = *(const short8*)&Gs[wr * 32 + mf * 16 + l15][s * 32 + l4 * 8];
#pragma unroll
        for (int nf = 0; nf < 4; ++nf)
            bfr[nf] = *(const short8*)(Wf + (((size_t)(s * 8 + wc * 4 + nf) * 64 + lane) * 8));
#pragma unroll
        for (int mf = 0; mf < 2; ++mf)
#pragma unroll
            for (int nf = 0; nf < 4; ++nf)
                acc[mf][nf] = __builtin_amdgcn_mfma_f32_16x16x32_bf16(af[mf], bfr[nf], acc[mf][nf], 0, 0, 0);
    }

    // ---- epilogue: bias + store (out is (B, COUT, E)) ----
    float bv[4];
#pragma unroll
    for (int nf = 0; nf < 4; ++nf) bv[nf] = bias[wc * 64 + nf * 16 + l15];
    float* ob = out + (size_t)b * COUT * E_;
    const bool full = (e0 + MTILE <= E_);
#pragma unroll
    for (int mf = 0; mf < 2; ++mf) {
        int erow = e0 + wr * 32 + mf * 16 + l4 * 4;
#pragma unroll
        for (int nf = 0; nf < 4; ++nf) {
            int o = wc * 64 + nf * 16 + l15;
            f32x4 v = acc[mf][nf];
            v = v + bv[nf];
            if (full) {
                *(f32x4*)(ob + (size_t)o * E_ + erow) = v;
            } else {
#pragma unroll
                for (int r = 0; r < 4; ++r)
                    if (erow + r < E_) ob[(size_t)o * E_ + erow + r] = v[r];
            }
        }
    }
}

extern "C" void kernel_launch(void* const* d_in, const int* in_sizes, int n_in,
                              void* d_out, int out_size, void* d_ws, size_t ws_size,
                              hipStream_t stream) {
    const float* x    = (const float*)d_in[0];
    const int*   em   = (const int*)d_in[1];
    const float* W    = (const float*)d_in[2];
    const float* bias = (const float*)d_in[3];
    float* out = (float*)d_out;

    unsigned short* f  = (unsigned short*)d_ws;                 // B*E*64 bf16 = 38.4 MB
    unsigned short* Wf = f + (size_t)B_ * E_ * CIN;             // 10*8*64*8 bf16 = 80 KB

    dim3 grid(NT_X, B_);
    transpose_kernel<<<grid, 256, 0, stream>>>(x, f);
    wconv_kernel<<<20, 256, 0, stream>>>(W, Wf);
    meshconv_kernel<<<grid, 256, 0, stream>>>(f, em, Wf, bias, out);
}

// Round 2
// 110.359 us; speedup vs baseline: 1.0334x; 1.0334x over previous
//
#include <hip/hip_runtime.h>
#include <hip/hip_bf16.h>

#define B_    4
#define CIN   64
#define E_    75000
#define K_    5
#define COUT  128
#define KTOT  320   // K_*CIN
#define MTILE 64
#define NT_X  1172  // ceil(E_/MTILE)

typedef __attribute__((ext_vector_type(8))) short short8;
typedef __attribute__((ext_vector_type(4))) float f32x4;

static __device__ __forceinline__ unsigned short f2bf(float f) {
    __hip_bfloat16 h = __float2bfloat16(f);
    union { __hip_bfloat16 h; unsigned short u; } cv; cv.h = h; return cv.u;
}
static __device__ __forceinline__ float bflo(unsigned int v) { return __uint_as_float(v << 16); }
static __device__ __forceinline__ float bfhi(unsigned int v) { return __uint_as_float(v & 0xffff0000u); }
// packed f32->bf16 RNE: D.lo = bf16(lo), D.hi = bf16(hi)  (1 VALU inst)
static __device__ __forceinline__ unsigned int cvtpk(float lo, float hi) {
    unsigned int r;
    asm("v_cvt_pk_bf16_f32 %0, %1, %2" : "=v"(r) : "v"(lo), "v"(hi));
    return r;
}

// ---------------- Kernel 1: x (B,CIN,E) f32 -> f (B,E,CIN) bf16 ----------------
__global__ __launch_bounds__(256) void transpose_kernel(const float* __restrict__ x,
                                                        unsigned short* __restrict__ f) {
    __shared__ float lds[64][65];
    const int b  = blockIdx.y;
    const int e0 = blockIdx.x * MTILE;
    const int tid = threadIdx.x;
    const int lane_e = tid & 63;
    const int cg = tid >> 6;                 // 0..3 channel group
    const int egc = min(e0 + lane_e, E_ - 1);
    const float* xb = x + (size_t)b * CIN * E_;
#pragma unroll
    for (int i = 0; i < 16; ++i) {
        int c = cg * 16 + i;
        lds[lane_e][c] = xb[(size_t)c * E_ + egc];
    }
    __syncthreads();
    const int e = tid >> 2;                  // 0..63
    const int q = tid & 3;                   // channels q*16..q*16+15
    if (e0 + e < E_) {
        unsigned short tmp[16] __attribute__((aligned(16)));
#pragma unroll
        for (int i = 0; i < 16; ++i) tmp[i] = f2bf(lds[e][q * 16 + i]);
        unsigned short* dst = f + ((size_t)b * E_ + e0 + e) * CIN + q * 16;
        *(short8*)dst       = *(short8*)&tmp[0];
        *(short8*)(dst + 8) = *(short8*)&tmp[8];
    }
}

// ------- Kernel 2: W (COUT, KTOT) f32 -> fragment-ordered bf16 Wf -------
// frag t = (s*8 + fidx)*64 + lane ; elem j = W[fidx*16 + (lane&15)][s*32 + (lane>>4)*8 + j]
__global__ void wconv_kernel(const float* __restrict__ W, unsigned short* __restrict__ Wf) {
    int t = blockIdx.x * 256 + threadIdx.x;
    if (t >= 10 * 8 * 64) return;
    int lane = t & 63;
    int fidx = (t >> 6) & 7;
    int s    = t >> 9;
    int row = fidx * 16 + (lane & 15);
    int col = s * 32 + (lane >> 4) * 8;
    const float* src = W + (size_t)row * KTOT + col;
    unsigned short tmp[8] __attribute__((aligned(16)));
#pragma unroll
    for (int j = 0; j < 8; ++j) tmp[j] = f2bf(src[j]);
    *(short8*)(Wf + (size_t)t * 8) = *(short8*)tmp;
}

// ---------------- Kernel 3: fused gather + G build + MFMA GEMM ----------------
// LDS: Gs = 64 rows x 160 dwords (320 bf16), XOR-swizzled: dw_idx ^= (row&7)<<2.
// 40960 B/block -> exactly 4 blocks/CU (160 KiB).
__global__ __launch_bounds__(256, 4) void meshconv_kernel(
    const unsigned short* __restrict__ f, const int* __restrict__ em,
    const unsigned short* __restrict__ Wf, const float* __restrict__ bias,
    float* __restrict__ out) {
    __shared__ unsigned int Gs[64 * 160];

    const int b  = blockIdx.y;
    const int e0 = blockIdx.x * MTILE;
    const int tid = threadIdx.x;
    const int w = tid >> 6, lane = tid & 63;
    const int eo = lane >> 5;            // which edge of the pair
    const int cu = lane & 31;            // uint (=2 channels) index

    // ---- stage 1: all edge indices into regs (broadcast 4B loads, L1) ----
    int idxv[8][K_];
    {
        const int* emb = em + (size_t)b * E_ * K_;
#pragma unroll
        for (int ep = 0; ep < 8; ++ep) {
            int er = e0 + w * 16 + ep * 2 + eo;
            er = er < E_ ? er : E_ - 1;
            const int* p = emb + (size_t)er * K_;
#pragma unroll
            for (int k = 0; k < K_; ++k) idxv[ep][k] = p[k];
        }
    }

    // ---- stage 2: all 40 gather loads in flight (32-bit voffset + SGPR base) ----
    unsigned int g[8][K_];
    {
        const unsigned int* fu = (const unsigned int*)(f + (size_t)b * E_ * CIN);
#pragma unroll
        for (int ep = 0; ep < 8; ++ep)
#pragma unroll
            for (int k = 0; k < K_; ++k)
                g[ep][k] = fu[(unsigned int)idxv[ep][k] * 32u + cu];
    }

    // ---- stage 3: build G rows in swizzled LDS ----
#pragma unroll
    for (int ep = 0; ep < 8; ++ep) {
        int el = w * 16 + ep * 2 + eo;
        unsigned int* grow = Gs + el * 160;
        int sw = (el & 7) << 2;
        float l1 = bflo(g[ep][1]), h1 = bfhi(g[ep][1]);
        float l2 = bflo(g[ep][2]), h2 = bfhi(g[ep][2]);
        float l3 = bflo(g[ep][3]), h3 = bfhi(g[ep][3]);
        float l4 = bflo(g[ep][4]), h4 = bfhi(g[ep][4]);
        grow[(0 * 32 + cu) ^ sw] = g[ep][0];
        grow[(1 * 32 + cu) ^ sw] = cvtpk(l1 + l3, h1 + h3);
        grow[(2 * 32 + cu) ^ sw] = cvtpk(l2 + l4, h2 + h4);
        grow[(3 * 32 + cu) ^ sw] = cvtpk(l1 - l3, h1 - h3) & 0x7fff7fffu;
        grow[(4 * 32 + cu) ^ sw] = cvtpk(l2 - l4, h2 - h4) & 0x7fff7fffu;
    }
    __syncthreads();

    // ---- stage 4: MFMA, 4 waves in 2x2; each wave 32 rows x 64 cols ----
    const int wr = w >> 1, wc = w & 1;
    const int l15 = lane & 15, l4g = lane >> 4;
    const int swz = (l15 & 7) << 2;      // row&7 == l15&7 (wr*32, mf*16 are 0 mod 8)
    f32x4 acc[2][4];
#pragma unroll
    for (int mf = 0; mf < 2; ++mf)
#pragma unroll
        for (int nf = 0; nf < 4; ++nf) acc[mf][nf] = (f32x4){0.f, 0.f, 0.f, 0.f};

#pragma unroll
    for (int s = 0; s < 10; ++s) {
        short8 af[2], bfr[4];
#pragma unroll
        for (int mf = 0; mf < 2; ++mf) {
            int row = wr * 32 + mf * 16 + l15;
            int col = (s * 16 + l4g * 4) ^ swz;
            af[mf] = *(const short8*)&Gs[row * 160 + col];
        }
#pragma unroll
        for (int nf = 0; nf < 4; ++nf)
            bfr[nf] = *(const short8*)(Wf + (((size_t)(s * 8 + wc * 4 + nf) * 64 + lane) * 8));
#pragma unroll
        for (int mf = 0; mf < 2; ++mf)
#pragma unroll
            for (int nf = 0; nf < 4; ++nf)
                acc[mf][nf] = __builtin_amdgcn_mfma_f32_16x16x32_bf16(af[mf], bfr[nf], acc[mf][nf], 0, 0, 0);
    }

    // ---- epilogue: bias + store (out is (B, COUT, E)) ----
    float bv[4];
#pragma unroll
    for (int nf = 0; nf < 4; ++nf) bv[nf] = bias[wc * 64 + nf * 16 + l15];
    float* ob = out + (size_t)b * COUT * E_;
    const bool full = (e0 + MTILE <= E_);
#pragma unroll
    for (int mf = 0; mf < 2; ++mf) {
        int erow = e0 + wr * 32 + mf * 16 + l4g * 4;
#pragma unroll
        for (int nf = 0; nf < 4; ++nf) {
            int o = wc * 64 + nf * 16 + l15;
            f32x4 v = acc[mf][nf];
            v = v + bv[nf];
            if (full) {
                *(f32x4*)(ob + (size_t)o * E_ + erow) = v;
            } else {
#pragma unroll
                for (int r = 0; r < 4; ++r)
                    if (erow + r < E_) ob[(size_t)o * E_ + erow + r] = v[r];
            }
        }
    }
}

extern "C" void kernel_launch(void* const* d_in, const int* in_sizes, int n_in,
                              void* d_out, int out_size, void* d_ws, size_t ws_size,
                              hipStream_t stream) {
    const float* x    = (const float*)d_in[0];
    const int*   em   = (const int*)d_in[1];
    const float* W    = (const float*)d_in[2];
    const float* bias = (const float*)d_in[3];
    float* out = (float*)d_out;

    unsigned short* f  = (unsigned short*)d_ws;                 // B*E*64 bf16 = 38.4 MB
    unsigned short* Wf = f + (size_t)B_ * E_ * CIN;             // 10*8*64*8 bf16 = 80 KB

    dim3 grid(NT_X, B_);
    transpose_kernel<<<grid, 256, 0, stream>>>(x, f);
    wconv_kernel<<<20, 256, 0, stream>>>(W, Wf);
    meshconv_kernel<<<grid, 256, 0, stream>>>(f, em, Wf, bias, out);
}